// Round 9
// baseline (302.814 us; speedup 1.0000x reference)
//
#include <hip/hip_runtime.h>
#include <math.h>

#define NN 100000
#define NE 1600000
#define EPB 8192   // edges per block in p1/p2 (R8: 2048; bigger runs -> fuller write sectors)
#define NEB 196    // ceil(NE/EPB)
#define NBUK 391   // node buckets of 256 nodes
#define CAP 8192   // max edges per bucket (mean 4092, sigma 64 -> +64 sigma)

#define DEGSCALE 16777216.0f   // 2^24 fixed-point for LDS deg accumulation

typedef __attribute__((ext_vector_type(8))) short bf16x8;
typedef __attribute__((ext_vector_type(4))) float f32x4;

#define MFMA(A, B, C) __builtin_amdgcn_mfma_f32_16x16x32_bf16(A, B, C, 0, 0, 0)

__device__ __forceinline__ float sigm(float z) { return 1.0f / (1.0f + expf(-z)); }

// Split fp32 into two truncated bf16 halves: v ~= hi + lo, |err| <~ 2^-16 |v|.
__device__ __forceinline__ void split1(float v, unsigned short* hi, unsigned short* lo) {
  unsigned u = __float_as_uint(v);
  *hi = (unsigned short)(u >> 16);
  float hf = __uint_as_float(u & 0xFFFF0000u);
  float lf = v - hf;
  *lo = (unsigned short)(__float_as_uint(lf) >> 16);
}

__device__ __forceinline__ void split8(const float* f, bf16x8* hi, bf16x8* lo) {
#pragma unroll
  for (int j = 0; j < 8; ++j) {
    unsigned short h, l;
    split1(f[j], &h, &l);
    (*hi)[j] = (short)h;
    (*lo)[j] = (short)l;
  }
}

__device__ __forceinline__ bf16x8 as_bf16x8(uint4 q) {
  union { uint4 q; bf16x8 v; } u;
  u.q = q;
  return u.v;
}

__device__ __forceinline__ void load8(const float4* p, int idx4, float* f) {
  float4 a = p[idx4];
  float4 b = p[idx4 + 1];
  f[0] = a.x; f[1] = a.y; f[2] = a.z; f[3] = a.w;
  f[4] = b.x; f[5] = b.y; f[6] = b.z; f[7] = b.w;
}

// ---- CSR build, zero global atomics ----

// Pass 1: per-block LDS histogram over 391 buckets; plain store of counts.
__global__ __launch_bounds__(256) void k_p1(const int* __restrict__ row,
                                            int* __restrict__ counts) {
  __shared__ int hist[NBUK];
  for (int i = threadIdx.x; i < NBUK; i += 256) hist[i] = 0;
  __syncthreads();
  int e0 = blockIdx.x * EPB;
  int e1 = min(e0 + EPB, NE);
  for (int e = e0 + (int)threadIdx.x; e < e1; e += 256)
    atomicAdd(&hist[row[e] >> 8], 1);
  __syncthreads();
  for (int i = threadIdx.x; i < NBUK; i += 256)
    counts[blockIdx.x * NBUK + i] = hist[i];
}

// Cross-block exclusive prefix per bucket (column scan of counts[NEB][NBUK]),
// in place; bucket totals out. Parallel 256-thread scan (NEB=196 <= 256).
__global__ __launch_bounds__(256) void k_s1(int* __restrict__ counts,
                                            int* __restrict__ total) {
  __shared__ int s[256];
  int b = blockIdx.x;
  int t = threadIdx.x;
  int v = (t < NEB) ? counts[t * NBUK + b] : 0;
  s[t] = v;
  __syncthreads();
  for (int o = 1; o < 256; o <<= 1) {
    int a = (t >= o) ? s[t - o] : 0;
    __syncthreads();
    s[t] += a;
    __syncthreads();
  }
  if (t < NEB) counts[t * NBUK + b] = s[t] - v;  // exclusive
  if (t == 255) total[b] = s[255];
}

// Exclusive scan of 391 bucket totals -> bases[392] (end sentinel NE).
__global__ __launch_bounds__(512) void k_s2(const int* __restrict__ total,
                                            int* __restrict__ bases) {
  __shared__ int s[512];
  int t = threadIdx.x;
  int v = (t < NBUK) ? total[t] : 0;
  s[t] = v;
  __syncthreads();
  for (int o = 1; o < 512; o <<= 1) {
    int a = (t >= o) ? s[t - o] : 0;
    __syncthreads();
    s[t] += a;
    __syncthreads();
  }
  if (t < NBUK) bases[t] = s[t] - v;
  if (t == 0) bases[NBUK] = NE;
}

// Pass 2: scatter edges into bucket-grouped order. Slot = bases[b] +
// rel[blk][b] + LDS-cursor (block-local returning atomic only).
__global__ __launch_bounds__(256) void k_p2(const int* __restrict__ row,
                                            const int* __restrict__ col,
                                            const float* __restrict__ ew,
                                            const int* __restrict__ rel,
                                            const int* __restrict__ bases,
                                            int2* __restrict__ colw) {
  __shared__ int cursor[NBUK];
  for (int i = threadIdx.x; i < NBUK; i += 256)
    cursor[i] = bases[i] + rel[blockIdx.x * NBUK + i];
  __syncthreads();
  int e0 = blockIdx.x * EPB;
  int e1 = min(e0 + EPB, NE);
  for (int e = e0 + (int)threadIdx.x; e < e1; e += 256) {
    int r = row[e];
    int c = col[e];
    float w = ew[e];
    int slot = atomicAdd(&cursor[r >> 8], 1);
    colw[slot] = make_int2(c | ((r & 255) << 17), __float_as_int(w));
  }
}

// One block per bucket: stage chunk in LDS, LDS count+deg, scan -> rowptr/dis,
// in-place re-scatter to row-sorted CSR. No global atomics anywhere.
__global__ __launch_bounds__(256) void k_bucket(const int* __restrict__ bases,
                                               int2* __restrict__ colw,
                                               int* __restrict__ rowptr,
                                               float* __restrict__ dis) {
  __shared__ int2 stage[CAP];   // 64 KB
  __shared__ int cnt[256], degfx[256], s[256], cursor[256];
  int b = blockIdx.x;
  int base = bases[b];
  int M = bases[b + 1] - base;
  if (M > CAP) M = CAP;  // unreachable for harness data (+64 sigma)
  int t = threadIdx.x;
  cnt[t] = 0;
  degfx[t] = 0;
  __syncthreads();
  for (int i = t; i < M; i += 256) {
    int2 e = colw[base + i];
    stage[i] = e;
    int rl = (e.x >> 17) & 255;
    atomicAdd(&cnt[rl], 1);
    unsigned fx = (unsigned)(__int_as_float(e.y) * DEGSCALE + 0.5f);
    atomicAdd((unsigned*)&degfx[rl], fx);
  }
  __syncthreads();
  int v = cnt[t];
  s[t] = v;
  __syncthreads();
  for (int o = 1; o < 256; o <<= 1) {
    int a = (t >= o) ? s[t - o] : 0;
    __syncthreads();
    s[t] += a;
    __syncthreads();
  }
  int excl = s[t] - v;
  int node = b * 256 + t;
  if (node <= NN) rowptr[node] = base + excl;
  if (node < NN) {
    unsigned fx = (unsigned)degfx[t];
    dis[node] = fx ? rsqrtf((float)fx * (1.0f / DEGSCALE)) : 0.0f;
  }
  cursor[t] = excl;
  __syncthreads();
  for (int i = t; i < M; i += 256) {
    int2 e = stage[i];
    int rl = (e.x >> 17) & 255;
    int r = atomicAdd(&cursor[rl], 1);
    colw[base + r] = e;  // safe: all reads staged before any write
  }
}

// Aggregation: one WAVE per node; agg[n] = dis[n] * sum(ew*dis[c]*h[c]).
// 32 edge-slots x 2 half-rows (slot=lane>>1, half=lane&1; each lane gathers
// 64 B of h). ~16 cache lines in flight per wave vs 8 in the R8 version —
// the gather is latency/MLP-bound (R8 post-mortem: 28% HBM, 22% VALU).
__global__ __launch_bounds__(256) void k_agg(const int* __restrict__ rowptr,
                                             const int2* __restrict__ colw,
                                             const float* __restrict__ dis,
                                             const float4* __restrict__ h4,
                                             float4* __restrict__ agg4) {
  int n = (blockIdx.x * 256 + threadIdx.x) >> 6;
  if (n >= NN) return;
  int lane = threadIdx.x & 63;
  int slot = lane >> 1;
  int half = lane & 1;
  int s0 = rowptr[n];
  int s1 = rowptr[n + 1];
  float4 acc0 = make_float4(0.f, 0.f, 0.f, 0.f);
  float4 acc1 = acc0, acc2 = acc0, acc3 = acc0;
  for (int j = s0 + slot; j < s1; j += 32) {
    int2 cw = colw[j];
    int c = cw.x & 0x1FFFF;
    float w = __int_as_float(cw.y) * dis[c];
    const float4* hp = h4 + c * 8 + half * 4;
    float4 h0 = hp[0], h1 = hp[1], h2 = hp[2], h3 = hp[3];
    acc0.x = fmaf(w, h0.x, acc0.x); acc0.y = fmaf(w, h0.y, acc0.y);
    acc0.z = fmaf(w, h0.z, acc0.z); acc0.w = fmaf(w, h0.w, acc0.w);
    acc1.x = fmaf(w, h1.x, acc1.x); acc1.y = fmaf(w, h1.y, acc1.y);
    acc1.z = fmaf(w, h1.z, acc1.z); acc1.w = fmaf(w, h1.w, acc1.w);
    acc2.x = fmaf(w, h2.x, acc2.x); acc2.y = fmaf(w, h2.y, acc2.y);
    acc2.z = fmaf(w, h2.z, acc2.z); acc2.w = fmaf(w, h2.w, acc2.w);
    acc3.x = fmaf(w, h3.x, acc3.x); acc3.y = fmaf(w, h3.y, acc3.y);
    acc3.z = fmaf(w, h3.z, acc3.z); acc3.w = fmaf(w, h3.w, acc3.w);
  }
#pragma unroll
  for (int o = 2; o < 64; o <<= 1) {
    acc0.x += __shfl_xor(acc0.x, o, 64); acc0.y += __shfl_xor(acc0.y, o, 64);
    acc0.z += __shfl_xor(acc0.z, o, 64); acc0.w += __shfl_xor(acc0.w, o, 64);
    acc1.x += __shfl_xor(acc1.x, o, 64); acc1.y += __shfl_xor(acc1.y, o, 64);
    acc1.z += __shfl_xor(acc1.z, o, 64); acc1.w += __shfl_xor(acc1.w, o, 64);
    acc2.x += __shfl_xor(acc2.x, o, 64); acc2.y += __shfl_xor(acc2.y, o, 64);
    acc2.z += __shfl_xor(acc2.z, o, 64); acc2.w += __shfl_xor(acc2.w, o, 64);
    acc3.x += __shfl_xor(acc3.x, o, 64); acc3.y += __shfl_xor(acc3.y, o, 64);
    acc3.z += __shfl_xor(acc3.z, o, 64); acc3.w += __shfl_xor(acc3.w, o, 64);
  }
  if (lane < 2) {
    float dn = dis[n];
    float4* ap = agg4 + n * 8 + half * 4;
    acc0.x *= dn; acc0.y *= dn; acc0.z *= dn; acc0.w *= dn;
    acc1.x *= dn; acc1.y *= dn; acc1.z *= dn; acc1.w *= dn;
    acc2.x *= dn; acc2.y *= dn; acc2.z *= dn; acc2.w *= dn;
    acc3.x *= dn; acc3.y *= dn; acc3.z *= dn; acc3.w *= dn;
    ap[0] = acc0; ap[1] = acc1; ap[2] = acc2; ap[3] = acc3;
  }
}

// ---- MFMA dense path (unchanged) ----
struct PrepParams {
  const float* W[4];
  const float* T0[4];
  const float* T1[4];
  const float* b[4];
  const float* cb[4];
  uint4* fh;
  uint4* fl;
  float* bias;  // [128] b+cb concatenated per gate
};

__global__ __launch_bounds__(256) void k_prep(PrepParams pp) {
  int idx = blockIdx.x * 256 + threadIdx.x;  // entry = T*64 + lane, 2048 total
  if (idx < 2048) {
    int T = idx >> 6;
    int lane = idx & 63;
    int ncol = ((T & 7) * 16) + (lane & 15);
    int g = ncol >> 5;
    int c = ncol & 31;
    int kq = (lane >> 4) * 8;
    const float* mat;
    int kbase;
    if (T < 16) { mat = pp.W[g]; kbase = (T >> 3) * 32 + kq; }
    else if (T < 24) { mat = pp.T0[g]; kbase = kq; }
    else { mat = pp.T1[g]; kbase = kq; }
    unsigned hw[4], lw[4];
#pragma unroll
    for (int jj = 0; jj < 4; ++jj) {
      unsigned short h0, l0, h1, l1;
      split1(mat[(kbase + 2 * jj) * 32 + c], &h0, &l0);
      split1(mat[(kbase + 2 * jj + 1) * 32 + c], &h1, &l1);
      hw[jj] = (unsigned)h0 | ((unsigned)h1 << 16);
      lw[jj] = (unsigned)l0 | ((unsigned)l1 << 16);
    }
    pp.fh[idx] = make_uint4(hw[0], hw[1], hw[2], hw[3]);
    pp.fl[idx] = make_uint4(lw[0], lw[1], lw[2], lw[3]);
  }
  if (blockIdx.x == 0 && threadIdx.x < 128) {
    int g = threadIdx.x >> 5;
    int c = threadIdx.x & 31;
    pp.bias[threadIdx.x] = pp.b[g][c] + pp.cb[g][c];
  }
}

struct GmmParams {
  const float4* x4;    // [N][16]
  const float4* h4;    // [N][8]
  const float4* agg4;  // [N][8]
  const float* cst;    // [N][32]
  const uint4* fh;
  const uint4* fl;
  const float* bias;   // [128]
  const float* wlin;   // [32]
  const float* blin;   // [1]
  float* out;          // [N]
};

__global__ __launch_bounds__(256) void k_gmm(GmmParams p) {
  const int lane = threadIdx.x & 63;
  const int wv = threadIdx.x >> 6;
  const int m0 = blockIdx.x * 64 + wv * 16;
  const int mr = lane & 15;
  const int quad = lane >> 4;
  int m = m0 + mr;
  if (m >= NN) m = NN - 1;

  bf16x8 xh[2], xl[2], hh, hl, gh, gl;
  float f[8];
#pragma unroll
  for (int kt = 0; kt < 2; ++kt) {
    load8(p.x4, (m * 64 + kt * 32 + quad * 8) >> 2, f);
    split8(f, &xh[kt], &xl[kt]);
  }
  load8(p.h4, (m * 32 + quad * 8) >> 2, f);
  split8(f, &hh, &hl);
  load8(p.agg4, (m * 32 + quad * 8) >> 2, f);
#pragma unroll
  for (int j = 0; j < 8; ++j) f[j] = -f[j];  // subtract agg@theta1
  split8(f, &gh, &gl);

  float wl0 = p.wlin[mr];
  float wl1 = p.wlin[mr + 16];
  float bl = p.blin[0];

  f32x4 acc[8];
#pragma unroll 2
  for (int nt = 0; nt < 8; ++nt) {
    float bv = p.bias[nt * 16 + mr];
    f32x4 a;
    a[0] = bv; a[1] = bv; a[2] = bv; a[3] = bv;
    bf16x8 b0h = as_bf16x8(p.fh[nt * 64 + lane]);
    bf16x8 b0l = as_bf16x8(p.fl[nt * 64 + lane]);
    bf16x8 b1h = as_bf16x8(p.fh[(8 + nt) * 64 + lane]);
    bf16x8 b1l = as_bf16x8(p.fl[(8 + nt) * 64 + lane]);
    bf16x8 t0h = as_bf16x8(p.fh[(16 + nt) * 64 + lane]);
    bf16x8 t0l = as_bf16x8(p.fl[(16 + nt) * 64 + lane]);
    bf16x8 t1h = as_bf16x8(p.fh[(24 + nt) * 64 + lane]);
    bf16x8 t1l = as_bf16x8(p.fl[(24 + nt) * 64 + lane]);
    a = MFMA(xh[0], b0h, a); a = MFMA(xh[0], b0l, a); a = MFMA(xl[0], b0h, a);
    a = MFMA(xh[1], b1h, a); a = MFMA(xh[1], b1l, a); a = MFMA(xl[1], b1h, a);
    a = MFMA(hh, t0h, a);    a = MFMA(hh, t0l, a);    a = MFMA(hl, t0h, a);
    a = MFMA(gh, t1h, a);    a = MFMA(gh, t1l, a);    a = MFMA(gl, t1h, a);
    acc[nt] = a;
  }

#pragma unroll
  for (int r = 0; r < 4; ++r) {
    int node = m0 + quad * 4 + r;
    int nc = node < NN ? node : NN - 1;
    float c0 = p.cst[nc * 32 + mr];
    float c1 = p.cst[nc * 32 + 16 + mr];
    float I0 = sigm(acc[0][r]), I1 = sigm(acc[1][r]);
    float F0 = sigm(acc[2][r]), F1 = sigm(acc[3][r]);
    float T0 = tanhf(acc[4][r]), T1 = tanhf(acc[5][r]);
    float O0 = sigm(acc[6][r]), O1 = sigm(acc[7][r]);
    float C0 = fmaf(F0, c0, I0 * T0);
    float C1 = fmaf(F1, c1, I1 * T1);
    float H0 = O0 * tanhf(C0);
    float H1 = O1 * tanhf(C1);
    float part = fmaf(fmaxf(H0, 0.f), wl0, fmaxf(H1, 0.f) * wl1);
#pragma unroll
    for (int s = 1; s < 16; s <<= 1) part += __shfl_xor(part, s, 64);
    if (mr == 0 && node < NN) p.out[node] = part + bl;
  }
}

extern "C" void kernel_launch(void* const* d_in, const int* in_sizes, int n_in,
                              void* d_out, int out_size, void* d_ws, size_t ws_size,
                              hipStream_t stream) {
  const float* x = (const float*)d_in[0];
  const int* row = (const int*)d_in[1];
  const int* col = row + NE;
  const float* ew = (const float*)d_in[2];
  const float* h = (const float*)d_in[3];
  const float* c = (const float*)d_in[4];

  // Workspace layout (4-byte units), total ~26.8 MB. No memset needed:
  // every word is written before it is read.
  float* ws = (float*)d_ws;
  float* dis = ws;                       // [0, 100000)
  int* rowptr = (int*)(ws + 100000);     // [100000, 200001)
  int* counts = (int*)(ws + 200004);     // NEB*NBUK = 76636
  int* total = (int*)(ws + 276640);      // 391
  int* bases = (int*)(ws + 277032);      // 392
  uint4* fh = (uint4*)(ws + 277424);     // 8192 floats (16B-aligned)
  uint4* fl = (uint4*)(ws + 285616);     // 8192 floats
  float* biasws = ws + 293808;           // 128
  int2* colw = (int2*)(ws + 293936);     // 2*NE floats = 12.8 MB (8B-aligned)
  float* agg = ws + 293936 + 2 * NE;     // 12.8 MB (16B-aligned)

  k_p1<<<NEB, 256, 0, stream>>>(row, counts);
  k_s1<<<NBUK, 256, 0, stream>>>(counts, total);
  k_s2<<<1, 512, 0, stream>>>(total, bases);
  k_p2<<<NEB, 256, 0, stream>>>(row, col, ew, counts, bases, colw);
  k_bucket<<<NBUK, 256, 0, stream>>>(bases, colw, rowptr, dis);

  PrepParams pp;
  for (int g = 0; g < 4; ++g) {
    pp.W[g] = (const float*)d_in[5 + 4 * g];
    pp.b[g] = (const float*)d_in[6 + 4 * g];
    pp.T0[g] = (const float*)d_in[7 + 4 * g];
    pp.T1[g] = pp.T0[g] + 1024;
    pp.cb[g] = (const float*)d_in[8 + 4 * g];
  }
  pp.fh = fh;
  pp.fl = fl;
  pp.bias = biasws;
  k_prep<<<8, 256, 0, stream>>>(pp);

  k_agg<<<(NN + 3) / 4, 256, 0, stream>>>(rowptr, colw, dis, (const float4*)h,
                                          (float4*)agg);

  GmmParams gp;
  gp.x4 = (const float4*)x;
  gp.h4 = (const float4*)h;
  gp.agg4 = (const float4*)agg;
  gp.cst = c;
  gp.fh = fh;
  gp.fl = fl;
  gp.bias = biasws;
  gp.wlin = (const float*)d_in[21];
  gp.blin = (const float*)d_in[22];
  gp.out = (float*)d_out;
  k_gmm<<<(NN + 63) / 64, 256, 0, stream>>>(gp);
}

// Round 10
// 256.348 us; speedup vs baseline: 1.1813x; 1.1813x over previous
//
#include <hip/hip_runtime.h>
#include <math.h>

#define NN 100000
#define NE 1600000
#define EPB 8192   // edges per block in p1/p2
#define NEB 196    // ceil(NE/EPB)
#define NBUK 391   // node buckets of 256 nodes
#define CAP 8192   // max edges per bucket (mean 4092, sigma 64 -> +64 sigma)

#define DEGSCALE 16777216.0f   // 2^24 fixed-point for LDS deg accumulation

typedef __attribute__((ext_vector_type(8))) short bf16x8;
typedef __attribute__((ext_vector_type(4))) float f32x4;

#define MFMA(A, B, C) __builtin_amdgcn_mfma_f32_16x16x32_bf16(A, B, C, 0, 0, 0)

__device__ __forceinline__ float sigm(float z) { return 1.0f / (1.0f + expf(-z)); }

// Split fp32 into two truncated bf16 halves: v ~= hi + lo, |err| <~ 2^-16 |v|.
__device__ __forceinline__ void split1(float v, unsigned short* hi, unsigned short* lo) {
  unsigned u = __float_as_uint(v);
  *hi = (unsigned short)(u >> 16);
  float hf = __uint_as_float(u & 0xFFFF0000u);
  float lf = v - hf;
  *lo = (unsigned short)(__float_as_uint(lf) >> 16);
}

__device__ __forceinline__ void split8(const float* f, bf16x8* hi, bf16x8* lo) {
#pragma unroll
  for (int j = 0; j < 8; ++j) {
    unsigned short h, l;
    split1(f[j], &h, &l);
    (*hi)[j] = (short)h;
    (*lo)[j] = (short)l;
  }
}

__device__ __forceinline__ bf16x8 as_bf16x8(uint4 q) {
  union { uint4 q; bf16x8 v; } u;
  u.q = q;
  return u.v;
}

__device__ __forceinline__ void load8(const float4* p, int idx4, float* f) {
  float4 a = p[idx4];
  float4 b = p[idx4 + 1];
  f[0] = a.x; f[1] = a.y; f[2] = a.z; f[3] = a.w;
  f[4] = b.x; f[5] = b.y; f[6] = b.z; f[7] = b.w;
}

// ---- CSR build, zero global atomics ----

// Pass 1: per-block LDS histogram over 391 buckets; plain store of counts.
__global__ __launch_bounds__(256) void k_p1(const int* __restrict__ row,
                                            int* __restrict__ counts) {
  __shared__ int hist[NBUK];
  for (int i = threadIdx.x; i < NBUK; i += 256) hist[i] = 0;
  __syncthreads();
  int e0 = blockIdx.x * EPB;
  int e1 = min(e0 + EPB, NE);
  for (int e = e0 + (int)threadIdx.x; e < e1; e += 256)
    atomicAdd(&hist[row[e] >> 8], 1);
  __syncthreads();
  for (int i = threadIdx.x; i < NBUK; i += 256)
    counts[blockIdx.x * NBUK + i] = hist[i];
}

// Cross-block exclusive prefix per bucket (column scan of counts[NEB][NBUK]),
// in place; bucket totals out. Parallel 256-thread scan (NEB=196 <= 256).
__global__ __launch_bounds__(256) void k_s1(int* __restrict__ counts,
                                            int* __restrict__ total) {
  __shared__ int s[256];
  int b = blockIdx.x;
  int t = threadIdx.x;
  int v = (t < NEB) ? counts[t * NBUK + b] : 0;
  s[t] = v;
  __syncthreads();
  for (int o = 1; o < 256; o <<= 1) {
    int a = (t >= o) ? s[t - o] : 0;
    __syncthreads();
    s[t] += a;
    __syncthreads();
  }
  if (t < NEB) counts[t * NBUK + b] = s[t] - v;  // exclusive
  if (t == 255) total[b] = s[255];
}

// Exclusive scan of 391 bucket totals -> bases[392] (end sentinel NE).
__global__ __launch_bounds__(512) void k_s2(const int* __restrict__ total,
                                            int* __restrict__ bases) {
  __shared__ int s[512];
  int t = threadIdx.x;
  int v = (t < NBUK) ? total[t] : 0;
  s[t] = v;
  __syncthreads();
  for (int o = 1; o < 512; o <<= 1) {
    int a = (t >= o) ? s[t - o] : 0;
    __syncthreads();
    s[t] += a;
    __syncthreads();
  }
  if (t < NBUK) bases[t] = s[t] - v;
  if (t == 0) bases[NBUK] = NE;
}

// Pass 2: scatter edges into bucket-grouped order. Slot = bases[b] +
// rel[blk][b] + LDS-cursor (block-local returning atomic only).
__global__ __launch_bounds__(256) void k_p2(const int* __restrict__ row,
                                            const int* __restrict__ col,
                                            const float* __restrict__ ew,
                                            const int* __restrict__ rel,
                                            const int* __restrict__ bases,
                                            int2* __restrict__ colw) {
  __shared__ int cursor[NBUK];
  for (int i = threadIdx.x; i < NBUK; i += 256)
    cursor[i] = bases[i] + rel[blockIdx.x * NBUK + i];
  __syncthreads();
  int e0 = blockIdx.x * EPB;
  int e1 = min(e0 + EPB, NE);
  for (int e = e0 + (int)threadIdx.x; e < e1; e += 256) {
    int r = row[e];
    int c = col[e];
    float w = ew[e];
    int slot = atomicAdd(&cursor[r >> 8], 1);
    colw[slot] = make_int2(c | ((r & 255) << 17), __float_as_int(w));
  }
}

// One block per bucket: stage chunk in LDS, LDS count+deg, scan -> rowptr/dis,
// in-place re-scatter to row-sorted CSR. No global atomics anywhere.
__global__ __launch_bounds__(256) void k_bucket(const int* __restrict__ bases,
                                               int2* __restrict__ colw,
                                               int* __restrict__ rowptr,
                                               float* __restrict__ dis) {
  __shared__ int2 stage[CAP];   // 64 KB
  __shared__ int cnt[256], degfx[256], s[256], cursor[256];
  int b = blockIdx.x;
  int base = bases[b];
  int M = bases[b + 1] - base;
  if (M > CAP) M = CAP;  // unreachable for harness data (+64 sigma)
  int t = threadIdx.x;
  cnt[t] = 0;
  degfx[t] = 0;
  __syncthreads();
  for (int i = t; i < M; i += 256) {
    int2 e = colw[base + i];
    stage[i] = e;
    int rl = (e.x >> 17) & 255;
    atomicAdd(&cnt[rl], 1);
    unsigned fx = (unsigned)(__int_as_float(e.y) * DEGSCALE + 0.5f);
    atomicAdd((unsigned*)&degfx[rl], fx);
  }
  __syncthreads();
  int v = cnt[t];
  s[t] = v;
  __syncthreads();
  for (int o = 1; o < 256; o <<= 1) {
    int a = (t >= o) ? s[t - o] : 0;
    __syncthreads();
    s[t] += a;
    __syncthreads();
  }
  int excl = s[t] - v;
  int node = b * 256 + t;
  if (node <= NN) rowptr[node] = base + excl;
  if (node < NN) {
    unsigned fx = (unsigned)degfx[t];
    dis[node] = fx ? rsqrtf((float)fx * (1.0f / DEGSCALE)) : 0.0f;
  }
  cursor[t] = excl;
  __syncthreads();
  for (int i = t; i < M; i += 256) {
    int2 e = stage[i];
    int rl = (e.x >> 17) & 255;
    int r = atomicAdd(&cursor[rl], 1);
    colw[base + r] = e;  // safe: all reads staged before any write
  }
}

// Aggregation: one WAVE per node; agg[n] = dis[n] * sum(ew*dis[c]*h[c]).
// R8 lane layout (8 edge-slots x 8 fg, coalesced 128 B/edge) + unroll-2 over
// the j-stride: doubles in-flight cache lines (8 -> 16) without changing
// instruction count per edge (R9 post-mortem: wider slot layouts double VALU
// overhead; ILP-unroll is the safe lever).
__global__ __launch_bounds__(256) void k_agg(const int* __restrict__ rowptr,
                                             const int2* __restrict__ colw,
                                             const float* __restrict__ dis,
                                             const float4* __restrict__ h4,
                                             float4* __restrict__ agg4) {
  int n = (blockIdx.x * 256 + threadIdx.x) >> 6;
  if (n >= NN) return;
  int lane = threadIdx.x & 63;
  int es = lane >> 3;
  int fg = lane & 7;
  int s0 = rowptr[n];
  int s1 = rowptr[n + 1];
  float4 a0 = make_float4(0.f, 0.f, 0.f, 0.f);
  float4 a1 = a0;
  int j = s0 + es;
  for (; j + 8 < s1; j += 16) {
    int2 cw0 = colw[j];
    int2 cw1 = colw[j + 8];
    int c0 = cw0.x & 0x1FFFF;
    int c1 = cw1.x & 0x1FFFF;
    float w0 = __int_as_float(cw0.y) * dis[c0];
    float w1 = __int_as_float(cw1.y) * dis[c1];
    float4 h0 = h4[c0 * 8 + fg];
    float4 h1 = h4[c1 * 8 + fg];
    a0.x = fmaf(w0, h0.x, a0.x); a0.y = fmaf(w0, h0.y, a0.y);
    a0.z = fmaf(w0, h0.z, a0.z); a0.w = fmaf(w0, h0.w, a0.w);
    a1.x = fmaf(w1, h1.x, a1.x); a1.y = fmaf(w1, h1.y, a1.y);
    a1.z = fmaf(w1, h1.z, a1.z); a1.w = fmaf(w1, h1.w, a1.w);
  }
  if (j < s1) {
    int2 cw0 = colw[j];
    int c0 = cw0.x & 0x1FFFF;
    float w0 = __int_as_float(cw0.y) * dis[c0];
    float4 h0 = h4[c0 * 8 + fg];
    a0.x = fmaf(w0, h0.x, a0.x); a0.y = fmaf(w0, h0.y, a0.y);
    a0.z = fmaf(w0, h0.z, a0.z); a0.w = fmaf(w0, h0.w, a0.w);
  }
  a0.x += a1.x; a0.y += a1.y; a0.z += a1.z; a0.w += a1.w;
#pragma unroll
  for (int o = 8; o < 64; o <<= 1) {
    a0.x += __shfl_xor(a0.x, o, 64);
    a0.y += __shfl_xor(a0.y, o, 64);
    a0.z += __shfl_xor(a0.z, o, 64);
    a0.w += __shfl_xor(a0.w, o, 64);
  }
  if (es == 0) {
    float dn = dis[n];
    a0.x *= dn; a0.y *= dn; a0.z *= dn; a0.w *= dn;
    agg4[n * 8 + fg] = a0;
  }
}

// ---- MFMA dense path (unchanged) ----
struct PrepParams {
  const float* W[4];
  const float* T0[4];
  const float* T1[4];
  const float* b[4];
  const float* cb[4];
  uint4* fh;
  uint4* fl;
  float* bias;  // [128] b+cb concatenated per gate
};

__global__ __launch_bounds__(256) void k_prep(PrepParams pp) {
  int idx = blockIdx.x * 256 + threadIdx.x;  // entry = T*64 + lane, 2048 total
  if (idx < 2048) {
    int T = idx >> 6;
    int lane = idx & 63;
    int ncol = ((T & 7) * 16) + (lane & 15);
    int g = ncol >> 5;
    int c = ncol & 31;
    int kq = (lane >> 4) * 8;
    const float* mat;
    int kbase;
    if (T < 16) { mat = pp.W[g]; kbase = (T >> 3) * 32 + kq; }
    else if (T < 24) { mat = pp.T0[g]; kbase = kq; }
    else { mat = pp.T1[g]; kbase = kq; }
    unsigned hw[4], lw[4];
#pragma unroll
    for (int jj = 0; jj < 4; ++jj) {
      unsigned short h0, l0, h1, l1;
      split1(mat[(kbase + 2 * jj) * 32 + c], &h0, &l0);
      split1(mat[(kbase + 2 * jj + 1) * 32 + c], &h1, &l1);
      hw[jj] = (unsigned)h0 | ((unsigned)h1 << 16);
      lw[jj] = (unsigned)l0 | ((unsigned)l1 << 16);
    }
    pp.fh[idx] = make_uint4(hw[0], hw[1], hw[2], hw[3]);
    pp.fl[idx] = make_uint4(lw[0], lw[1], lw[2], lw[3]);
  }
  if (blockIdx.x == 0 && threadIdx.x < 128) {
    int g = threadIdx.x >> 5;
    int c = threadIdx.x & 31;
    pp.bias[threadIdx.x] = pp.b[g][c] + pp.cb[g][c];
  }
}

struct GmmParams {
  const float4* x4;    // [N][16]
  const float4* h4;    // [N][8]
  const float4* agg4;  // [N][8]
  const float* cst;    // [N][32]
  const uint4* fh;
  const uint4* fl;
  const float* bias;   // [128]
  const float* wlin;   // [32]
  const float* blin;   // [1]
  float* out;          // [N]
};

__global__ __launch_bounds__(256) void k_gmm(GmmParams p) {
  const int lane = threadIdx.x & 63;
  const int wv = threadIdx.x >> 6;
  const int m0 = blockIdx.x * 64 + wv * 16;
  const int mr = lane & 15;
  const int quad = lane >> 4;
  int m = m0 + mr;
  if (m >= NN) m = NN - 1;

  bf16x8 xh[2], xl[2], hh, hl, gh, gl;
  float f[8];
#pragma unroll
  for (int kt = 0; kt < 2; ++kt) {
    load8(p.x4, (m * 64 + kt * 32 + quad * 8) >> 2, f);
    split8(f, &xh[kt], &xl[kt]);
  }
  load8(p.h4, (m * 32 + quad * 8) >> 2, f);
  split8(f, &hh, &hl);
  load8(p.agg4, (m * 32 + quad * 8) >> 2, f);
#pragma unroll
  for (int j = 0; j < 8; ++j) f[j] = -f[j];  // subtract agg@theta1
  split8(f, &gh, &gl);

  float wl0 = p.wlin[mr];
  float wl1 = p.wlin[mr + 16];
  float bl = p.blin[0];

  f32x4 acc[8];
#pragma unroll 2
  for (int nt = 0; nt < 8; ++nt) {
    float bv = p.bias[nt * 16 + mr];
    f32x4 a;
    a[0] = bv; a[1] = bv; a[2] = bv; a[3] = bv;
    bf16x8 b0h = as_bf16x8(p.fh[nt * 64 + lane]);
    bf16x8 b0l = as_bf16x8(p.fl[nt * 64 + lane]);
    bf16x8 b1h = as_bf16x8(p.fh[(8 + nt) * 64 + lane]);
    bf16x8 b1l = as_bf16x8(p.fl[(8 + nt) * 64 + lane]);
    bf16x8 t0h = as_bf16x8(p.fh[(16 + nt) * 64 + lane]);
    bf16x8 t0l = as_bf16x8(p.fl[(16 + nt) * 64 + lane]);
    bf16x8 t1h = as_bf16x8(p.fh[(24 + nt) * 64 + lane]);
    bf16x8 t1l = as_bf16x8(p.fl[(24 + nt) * 64 + lane]);
    a = MFMA(xh[0], b0h, a); a = MFMA(xh[0], b0l, a); a = MFMA(xl[0], b0h, a);
    a = MFMA(xh[1], b1h, a); a = MFMA(xh[1], b1l, a); a = MFMA(xl[1], b1h, a);
    a = MFMA(hh, t0h, a);    a = MFMA(hh, t0l, a);    a = MFMA(hl, t0h, a);
    a = MFMA(gh, t1h, a);    a = MFMA(gh, t1l, a);    a = MFMA(gl, t1h, a);
    acc[nt] = a;
  }

#pragma unroll
  for (int r = 0; r < 4; ++r) {
    int node = m0 + quad * 4 + r;
    int nc = node < NN ? node : NN - 1;
    float c0 = p.cst[nc * 32 + mr];
    float c1 = p.cst[nc * 32 + 16 + mr];
    float I0 = sigm(acc[0][r]), I1 = sigm(acc[1][r]);
    float F0 = sigm(acc[2][r]), F1 = sigm(acc[3][r]);
    float T0 = tanhf(acc[4][r]), T1 = tanhf(acc[5][r]);
    float O0 = sigm(acc[6][r]), O1 = sigm(acc[7][r]);
    float C0 = fmaf(F0, c0, I0 * T0);
    float C1 = fmaf(F1, c1, I1 * T1);
    float H0 = O0 * tanhf(C0);
    float H1 = O1 * tanhf(C1);
    float part = fmaf(fmaxf(H0, 0.f), wl0, fmaxf(H1, 0.f) * wl1);
#pragma unroll
    for (int s = 1; s < 16; s <<= 1) part += __shfl_xor(part, s, 64);
    if (mr == 0 && node < NN) p.out[node] = part + bl;
  }
}

extern "C" void kernel_launch(void* const* d_in, const int* in_sizes, int n_in,
                              void* d_out, int out_size, void* d_ws, size_t ws_size,
                              hipStream_t stream) {
  const float* x = (const float*)d_in[0];
  const int* row = (const int*)d_in[1];
  const int* col = row + NE;
  const float* ew = (const float*)d_in[2];
  const float* h = (const float*)d_in[3];
  const float* c = (const float*)d_in[4];

  // Workspace layout (4-byte units), total ~26.8 MB. No memset needed:
  // every word is written before it is read.
  float* ws = (float*)d_ws;
  float* dis = ws;                       // [0, 100000)
  int* rowptr = (int*)(ws + 100000);     // [100000, 200001)
  int* counts = (int*)(ws + 200004);     // NEB*NBUK = 76636
  int* total = (int*)(ws + 276640);      // 391
  int* bases = (int*)(ws + 277032);      // 392
  uint4* fh = (uint4*)(ws + 277424);     // 8192 floats (16B-aligned)
  uint4* fl = (uint4*)(ws + 285616);     // 8192 floats
  float* biasws = ws + 293808;           // 128
  int2* colw = (int2*)(ws + 293936);     // 2*NE floats = 12.8 MB (8B-aligned)
  float* agg = ws + 293936 + 2 * NE;     // 12.8 MB (16B-aligned)

  k_p1<<<NEB, 256, 0, stream>>>(row, counts);
  k_s1<<<NBUK, 256, 0, stream>>>(counts, total);
  k_s2<<<1, 512, 0, stream>>>(total, bases);
  k_p2<<<NEB, 256, 0, stream>>>(row, col, ew, counts, bases, colw);
  k_bucket<<<NBUK, 256, 0, stream>>>(bases, colw, rowptr, dis);

  PrepParams pp;
  for (int g = 0; g < 4; ++g) {
    pp.W[g] = (const float*)d_in[5 + 4 * g];
    pp.b[g] = (const float*)d_in[6 + 4 * g];
    pp.T0[g] = (const float*)d_in[7 + 4 * g];
    pp.T1[g] = pp.T0[g] + 1024;
    pp.cb[g] = (const float*)d_in[8 + 4 * g];
  }
  pp.fh = fh;
  pp.fl = fl;
  pp.bias = biasws;
  k_prep<<<8, 256, 0, stream>>>(pp);

  k_agg<<<(NN + 3) / 4, 256, 0, stream>>>(rowptr, colw, dis, (const float4*)h,
                                          (float4*)agg);

  GmmParams gp;
  gp.x4 = (const float4*)x;
  gp.h4 = (const float4*)h;
  gp.agg4 = (const float4*)agg;
  gp.cst = c;
  gp.fh = fh;
  gp.fl = fl;
  gp.bias = biasws;
  gp.wlin = (const float*)d_in[21];
  gp.blin = (const float*)d_in[22];
  gp.out = (float*)d_out;
  k_gmm<<<(NN + 63) / 64, 256, 0, stream>>>(gp);
}

// Round 11
// 250.775 us; speedup vs baseline: 1.2075x; 1.0222x over previous
//
#include <hip/hip_runtime.h>
#include <math.h>

#define NN 100000
#define NE 1600000
#define EPB 8192   // edges per block in p1/p2
#define NEB 196    // ceil(NE/EPB)
#define NBUK 391   // node buckets of 256 nodes
#define CAP 8192   // max edges per bucket (mean 4092, sigma 64 -> +64 sigma)

#define DEGSCALE 16777216.0f   // 2^24 fixed-point for LDS deg accumulation

typedef __attribute__((ext_vector_type(8))) short bf16x8;
typedef __attribute__((ext_vector_type(4))) float f32x4;

#define MFMA(A, B, C) __builtin_amdgcn_mfma_f32_16x16x32_bf16(A, B, C, 0, 0, 0)

__device__ __forceinline__ float sigm(float z) { return 1.0f / (1.0f + expf(-z)); }

// Split fp32 into two truncated bf16 halves: v ~= hi + lo, |err| <~ 2^-16 |v|.
__device__ __forceinline__ void split1(float v, unsigned short* hi, unsigned short* lo) {
  unsigned u = __float_as_uint(v);
  *hi = (unsigned short)(u >> 16);
  float hf = __uint_as_float(u & 0xFFFF0000u);
  float lf = v - hf;
  *lo = (unsigned short)(__float_as_uint(lf) >> 16);
}

__device__ __forceinline__ void split8(const float* f, bf16x8* hi, bf16x8* lo) {
#pragma unroll
  for (int j = 0; j < 8; ++j) {
    unsigned short h, l;
    split1(f[j], &h, &l);
    (*hi)[j] = (short)h;
    (*lo)[j] = (short)l;
  }
}

__device__ __forceinline__ bf16x8 as_bf16x8(uint4 q) {
  union { uint4 q; bf16x8 v; } u;
  u.q = q;
  return u.v;
}

__device__ __forceinline__ void load8(const float4* p, int idx4, float* f) {
  float4 a = p[idx4];
  float4 b = p[idx4 + 1];
  f[0] = a.x; f[1] = a.y; f[2] = a.z; f[3] = a.w;
  f[4] = b.x; f[5] = b.y; f[6] = b.z; f[7] = b.w;
}

// ---- CSR build, zero global atomics ----

// Pass 1: per-block LDS histogram over 391 buckets; plain store of counts.
__global__ __launch_bounds__(256) void k_p1(const int* __restrict__ row,
                                            int* __restrict__ counts) {
  __shared__ int hist[NBUK];
  for (int i = threadIdx.x; i < NBUK; i += 256) hist[i] = 0;
  __syncthreads();
  int e0 = blockIdx.x * EPB;
  int e1 = min(e0 + EPB, NE);
  for (int e = e0 + (int)threadIdx.x; e < e1; e += 256)
    atomicAdd(&hist[row[e] >> 8], 1);
  __syncthreads();
  for (int i = threadIdx.x; i < NBUK; i += 256)
    counts[blockIdx.x * NBUK + i] = hist[i];
}

// Cross-block exclusive prefix per bucket (column scan of counts[NEB][NBUK]),
// in place; bucket totals out. Parallel 256-thread scan (NEB=196 <= 256).
__global__ __launch_bounds__(256) void k_s1(int* __restrict__ counts,
                                            int* __restrict__ total) {
  __shared__ int s[256];
  int b = blockIdx.x;
  int t = threadIdx.x;
  int v = (t < NEB) ? counts[t * NBUK + b] : 0;
  s[t] = v;
  __syncthreads();
  for (int o = 1; o < 256; o <<= 1) {
    int a = (t >= o) ? s[t - o] : 0;
    __syncthreads();
    s[t] += a;
    __syncthreads();
  }
  if (t < NEB) counts[t * NBUK + b] = s[t] - v;  // exclusive
  if (t == 255) total[b] = s[255];
}

// Weight-fragment prep params (merged into k_s2p: block 0 scans bucket totals,
// blocks 1..8 build the MFMA B-fragments).
struct S2PParams {
  const int* total;
  int* bases;
  const float* W[4];
  const float* T0[4];
  const float* T1[4];
  const float* b[4];
  const float* cb[4];
  uint4* fh;
  uint4* fl;
  float* bias;  // [128] b+cb concatenated per gate
};

__global__ __launch_bounds__(512) void k_s2p(S2PParams pp) {
  if (blockIdx.x == 0) {
    // Exclusive scan of 391 bucket totals -> bases[392] (end sentinel NE).
    __shared__ int s[512];
    int t = threadIdx.x;
    int v = (t < NBUK) ? pp.total[t] : 0;
    s[t] = v;
    __syncthreads();
    for (int o = 1; o < 512; o <<= 1) {
      int a = (t >= o) ? s[t - o] : 0;
      __syncthreads();
      s[t] += a;
      __syncthreads();
    }
    if (t < NBUK) pp.bases[t] = s[t] - v;
    if (t == 0) pp.bases[NBUK] = NE;
    return;
  }
  // Prep: entry = T*64 + lane, 2048 total.
  // Tiles T: 0..15 x-W (K=64), 16..23 theta0, 24..31 theta1.
  // Fragment layout: B[k = quad*8+j][n = (T&7)*16 + (lane&15)].
  int idx = (blockIdx.x - 1) * 512 + threadIdx.x;
  if (idx < 2048) {
    int T = idx >> 6;
    int lane = idx & 63;
    int ncol = ((T & 7) * 16) + (lane & 15);
    int g = ncol >> 5;
    int c = ncol & 31;
    int kq = (lane >> 4) * 8;
    const float* mat;
    int kbase;
    if (T < 16) { mat = pp.W[g]; kbase = (T >> 3) * 32 + kq; }
    else if (T < 24) { mat = pp.T0[g]; kbase = kq; }
    else { mat = pp.T1[g]; kbase = kq; }
    unsigned hw[4], lw[4];
#pragma unroll
    for (int jj = 0; jj < 4; ++jj) {
      unsigned short h0, l0, h1, l1;
      split1(mat[(kbase + 2 * jj) * 32 + c], &h0, &l0);
      split1(mat[(kbase + 2 * jj + 1) * 32 + c], &h1, &l1);
      hw[jj] = (unsigned)h0 | ((unsigned)h1 << 16);
      lw[jj] = (unsigned)l0 | ((unsigned)l1 << 16);
    }
    pp.fh[idx] = make_uint4(hw[0], hw[1], hw[2], hw[3]);
    pp.fl[idx] = make_uint4(lw[0], lw[1], lw[2], lw[3]);
  }
  if (blockIdx.x == 1 && threadIdx.x < 128) {
    int g = threadIdx.x >> 5;
    int c = threadIdx.x & 31;
    pp.bias[threadIdx.x] = pp.b[g][c] + pp.cb[g][c];
  }
}

// Pass 2: scatter edges into bucket-grouped order. Slot = bases[b] +
// rel[blk][b] + LDS-cursor (block-local returning atomic only).
__global__ __launch_bounds__(256) void k_p2(const int* __restrict__ row,
                                            const int* __restrict__ col,
                                            const float* __restrict__ ew,
                                            const int* __restrict__ rel,
                                            const int* __restrict__ bases,
                                            int2* __restrict__ colw) {
  __shared__ int cursor[NBUK];
  for (int i = threadIdx.x; i < NBUK; i += 256)
    cursor[i] = bases[i] + rel[blockIdx.x * NBUK + i];
  __syncthreads();
  int e0 = blockIdx.x * EPB;
  int e1 = min(e0 + EPB, NE);
  for (int e = e0 + (int)threadIdx.x; e < e1; e += 256) {
    int r = row[e];
    int c = col[e];
    float w = ew[e];
    int slot = atomicAdd(&cursor[r >> 8], 1);
    colw[slot] = make_int2(c | ((r & 255) << 17), __float_as_int(w));
  }
}

// One block per bucket: stage chunk in LDS, LDS count+deg, scan -> rowptr/dis,
// in-place re-scatter to row-sorted CSR. No global atomics anywhere.
__global__ __launch_bounds__(256) void k_bucket(const int* __restrict__ bases,
                                               int2* __restrict__ colw,
                                               int* __restrict__ rowptr,
                                               float* __restrict__ dis) {
  __shared__ int2 stage[CAP];   // 64 KB
  __shared__ int cnt[256], degfx[256], s[256], cursor[256];
  int b = blockIdx.x;
  int base = bases[b];
  int M = bases[b + 1] - base;
  if (M > CAP) M = CAP;  // unreachable for harness data (+64 sigma)
  int t = threadIdx.x;
  cnt[t] = 0;
  degfx[t] = 0;
  __syncthreads();
  for (int i = t; i < M; i += 256) {
    int2 e = colw[base + i];
    stage[i] = e;
    int rl = (e.x >> 17) & 255;
    atomicAdd(&cnt[rl], 1);
    unsigned fx = (unsigned)(__int_as_float(e.y) * DEGSCALE + 0.5f);
    atomicAdd((unsigned*)&degfx[rl], fx);
  }
  __syncthreads();
  int v = cnt[t];
  s[t] = v;
  __syncthreads();
  for (int o = 1; o < 256; o <<= 1) {
    int a = (t >= o) ? s[t - o] : 0;
    __syncthreads();
    s[t] += a;
    __syncthreads();
  }
  int excl = s[t] - v;
  int node = b * 256 + t;
  if (node <= NN) rowptr[node] = base + excl;
  if (node < NN) {
    unsigned fx = (unsigned)degfx[t];
    dis[node] = fx ? rsqrtf((float)fx * (1.0f / DEGSCALE)) : 0.0f;
  }
  cursor[t] = excl;
  __syncthreads();
  for (int i = t; i < M; i += 256) {
    int2 e = stage[i];
    int rl = (e.x >> 17) & 255;
    int r = atomicAdd(&cursor[rl], 1);
    colw[base + r] = e;  // safe: all reads staged before any write
  }
}

// ---- Fused aggregation + MFMA gates kernel ----
// One wave per 16 nodes. Phase A: lane (mr,quad) walks node m0+mr's CSR list
// accumulating sum(w * h[c][quad*8+j]) for j=0..7 — this IS the MFMA
// A-fragment layout A[m=lane&15][k=quad*8+j], so no reduction, no LDS, no
// global agg round-trip (R10 post-mortem: k_agg 44us + k_gmm 43us were both
// latency-bound with a pointless 25.6 MB hand-off between them).
struct FusedParams {
  const float4* x4;    // [N][16]
  const float4* h4;    // [N][8]
  const float* cst;    // [N][32]
  const int* rowptr;   // [N+1]
  const int2* colw;    // [E] row-sorted {col|rowlocal<<17, ew}
  const float* dis;    // [N]
  const uint4* fh;
  const uint4* fl;
  const float* bias;   // [128]
  const float* wlin;   // [32]
  const float* blin;   // [1]
  float* out;          // [N]
};

__global__ __launch_bounds__(256) void k_fused(FusedParams p) {
  const int lane = threadIdx.x & 63;
  const int wv = threadIdx.x >> 6;
  const int m0 = blockIdx.x * 64 + wv * 16;
  const int mr = lane & 15;
  const int quad = lane >> 4;
  int m = m0 + mr;
  if (m >= NN) m = NN - 1;

  // Dense A inputs: x (K=64) and h (K=32), split to bf16 hi/lo.
  bf16x8 xh[2], xl[2], hh, hl, gh, gl;
  float f[8];
#pragma unroll
  for (int kt = 0; kt < 2; ++kt) {
    load8(p.x4, (m * 64 + kt * 32 + quad * 8) >> 2, f);
    split8(f, &xh[kt], &xl[kt]);
  }
  load8(p.h4, (m * 32 + quad * 8) >> 2, f);
  split8(f, &hh, &hl);

  // Phase A: CSR gather directly into A-fragment registers. Unroll-2 with
  // two accumulator sets for MLP (R10: ILP-unroll is the safe lever).
  float fa[8] = {0.f, 0.f, 0.f, 0.f, 0.f, 0.f, 0.f, 0.f};
  float fb[8] = {0.f, 0.f, 0.f, 0.f, 0.f, 0.f, 0.f, 0.f};
  {
    int s0 = p.rowptr[m];
    int s1v = p.rowptr[m + 1];
    int j = s0;
    for (; j + 1 < s1v; j += 2) {
      int2 cw0 = p.colw[j];
      int2 cw1 = p.colw[j + 1];
      int c0 = cw0.x & 0x1FFFF;
      int c1 = cw1.x & 0x1FFFF;
      float w0 = __int_as_float(cw0.y) * p.dis[c0];
      float w1 = __int_as_float(cw1.y) * p.dis[c1];
      const float4* hp0 = p.h4 + c0 * 8 + quad * 2;
      const float4* hp1 = p.h4 + c1 * 8 + quad * 2;
      float4 a0 = hp0[0], a1 = hp0[1];
      float4 b0 = hp1[0], b1 = hp1[1];
      fa[0] = fmaf(w0, a0.x, fa[0]); fa[1] = fmaf(w0, a0.y, fa[1]);
      fa[2] = fmaf(w0, a0.z, fa[2]); fa[3] = fmaf(w0, a0.w, fa[3]);
      fa[4] = fmaf(w0, a1.x, fa[4]); fa[5] = fmaf(w0, a1.y, fa[5]);
      fa[6] = fmaf(w0, a1.z, fa[6]); fa[7] = fmaf(w0, a1.w, fa[7]);
      fb[0] = fmaf(w1, b0.x, fb[0]); fb[1] = fmaf(w1, b0.y, fb[1]);
      fb[2] = fmaf(w1, b0.z, fb[2]); fb[3] = fmaf(w1, b0.w, fb[3]);
      fb[4] = fmaf(w1, b1.x, fb[4]); fb[5] = fmaf(w1, b1.y, fb[5]);
      fb[6] = fmaf(w1, b1.z, fb[6]); fb[7] = fmaf(w1, b1.w, fb[7]);
    }
    if (j < s1v) {
      int2 cw0 = p.colw[j];
      int c0 = cw0.x & 0x1FFFF;
      float w0 = __int_as_float(cw0.y) * p.dis[c0];
      const float4* hp0 = p.h4 + c0 * 8 + quad * 2;
      float4 a0 = hp0[0], a1 = hp0[1];
      fa[0] = fmaf(w0, a0.x, fa[0]); fa[1] = fmaf(w0, a0.y, fa[1]);
      fa[2] = fmaf(w0, a0.z, fa[2]); fa[3] = fmaf(w0, a0.w, fa[3]);
      fa[4] = fmaf(w0, a1.x, fa[4]); fa[5] = fmaf(w0, a1.y, fa[5]);
      fa[6] = fmaf(w0, a1.z, fa[6]); fa[7] = fmaf(w0, a1.w, fa[7]);
    }
  }
  {
    float dn = -p.dis[m];  // negative: z -= agg @ theta1
#pragma unroll
    for (int j = 0; j < 8; ++j) f[j] = dn * (fa[j] + fb[j]);
    split8(f, &gh, &gl);
  }

  float wl0 = p.wlin[mr];
  float wl1 = p.wlin[mr + 16];
  float bl = p.blin[0];

  f32x4 acc[8];
#pragma unroll 2
  for (int nt = 0; nt < 8; ++nt) {
    float bv = p.bias[nt * 16 + mr];
    f32x4 a;
    a[0] = bv; a[1] = bv; a[2] = bv; a[3] = bv;
    bf16x8 b0h = as_bf16x8(p.fh[nt * 64 + lane]);
    bf16x8 b0l = as_bf16x8(p.fl[nt * 64 + lane]);
    bf16x8 b1h = as_bf16x8(p.fh[(8 + nt) * 64 + lane]);
    bf16x8 b1l = as_bf16x8(p.fl[(8 + nt) * 64 + lane]);
    bf16x8 t0h = as_bf16x8(p.fh[(16 + nt) * 64 + lane]);
    bf16x8 t0l = as_bf16x8(p.fl[(16 + nt) * 64 + lane]);
    bf16x8 t1h = as_bf16x8(p.fh[(24 + nt) * 64 + lane]);
    bf16x8 t1l = as_bf16x8(p.fl[(24 + nt) * 64 + lane]);
    a = MFMA(xh[0], b0h, a); a = MFMA(xh[0], b0l, a); a = MFMA(xl[0], b0h, a);
    a = MFMA(xh[1], b1h, a); a = MFMA(xh[1], b1l, a); a = MFMA(xl[1], b1h, a);
    a = MFMA(hh, t0h, a);    a = MFMA(hh, t0l, a);    a = MFMA(hl, t0h, a);
    a = MFMA(gh, t1h, a);    a = MFMA(gh, t1l, a);    a = MFMA(gl, t1h, a);
    acc[nt] = a;
  }

  // Epilogue: lane holds cols mr (tile 2g) and mr+16 (tile 2g+1) of gate g,
  // rows quad*4+r. All four gates' z in-lane.
#pragma unroll
  for (int r = 0; r < 4; ++r) {
    int node = m0 + quad * 4 + r;
    int nc = node < NN ? node : NN - 1;
    float c0 = p.cst[nc * 32 + mr];
    float c1 = p.cst[nc * 32 + 16 + mr];
    float I0 = sigm(acc[0][r]), I1 = sigm(acc[1][r]);
    float F0 = sigm(acc[2][r]), F1 = sigm(acc[3][r]);
    float T0 = tanhf(acc[4][r]), T1 = tanhf(acc[5][r]);
    float O0 = sigm(acc[6][r]), O1 = sigm(acc[7][r]);
    float C0 = fmaf(F0, c0, I0 * T0);
    float C1 = fmaf(F1, c1, I1 * T1);
    float H0 = O0 * tanhf(C0);
    float H1 = O1 * tanhf(C1);
    float part = fmaf(fmaxf(H0, 0.f), wl0, fmaxf(H1, 0.f) * wl1);
#pragma unroll
    for (int s = 1; s < 16; s <<= 1) part += __shfl_xor(part, s, 64);
    if (mr == 0 && node < NN) p.out[node] = part + bl;
  }
}

extern "C" void kernel_launch(void* const* d_in, const int* in_sizes, int n_in,
                              void* d_out, int out_size, void* d_ws, size_t ws_size,
                              hipStream_t stream) {
  const float* x = (const float*)d_in[0];
  const int* row = (const int*)d_in[1];
  const int* col = row + NE;
  const float* ew = (const float*)d_in[2];
  const float* h = (const float*)d_in[3];
  const float* c = (const float*)d_in[4];

  // Workspace layout (4-byte units), total ~14 MB. No memset needed:
  // every word is written before it is read.
  float* ws = (float*)d_ws;
  float* dis = ws;                       // [0, 100000)
  int* rowptr = (int*)(ws + 100000);     // [100000, 200001)
  int* counts = (int*)(ws + 200004);     // NEB*NBUK = 76636
  int* total = (int*)(ws + 276640);      // 391
  int* bases = (int*)(ws + 277032);      // 392
  uint4* fh = (uint4*)(ws + 277424);     // 8192 floats (16B-aligned)
  uint4* fl = (uint4*)(ws + 285616);     // 8192 floats
  float* biasws = ws + 293808;           // 128
  int2* colw = (int2*)(ws + 293936);     // 2*NE floats = 12.8 MB (8B-aligned)

  k_p1<<<NEB, 256, 0, stream>>>(row, counts);
  k_s1<<<NBUK, 256, 0, stream>>>(counts, total);

  S2PParams sp;
  sp.total = total;
  sp.bases = bases;
  for (int g = 0; g < 4; ++g) {
    sp.W[g] = (const float*)d_in[5 + 4 * g];
    sp.b[g] = (const float*)d_in[6 + 4 * g];
    sp.T0[g] = (const float*)d_in[7 + 4 * g];
    sp.T1[g] = sp.T0[g] + 1024;
    sp.cb[g] = (const float*)d_in[8 + 4 * g];
  }
  sp.fh = fh;
  sp.fl = fl;
  sp.bias = biasws;
  k_s2p<<<9, 512, 0, stream>>>(sp);

  k_p2<<<NEB, 256, 0, stream>>>(row, col, ew, counts, bases, colw);
  k_bucket<<<NBUK, 256, 0, stream>>>(bases, colw, rowptr, dis);

  FusedParams fp;
  fp.x4 = (const float4*)x;
  fp.h4 = (const float4*)h;
  fp.cst = c;
  fp.rowptr = rowptr;
  fp.colw = colw;
  fp.dis = dis;
  fp.fh = fh;
  fp.fl = fl;
  fp.bias = biasws;
  fp.wlin = (const float*)d_in[21];
  fp.blin = (const float*)d_in[22];
  fp.out = (float*)d_out;
  k_fused<<<(NN + 63) / 64, 256, 0, stream>>>(fp);
}